// Round 3
// baseline (244.824 us; speedup 1.0000x reference)
//
#include <hip/hip_runtime.h>
#include <stdint.h>

// ---- Paillier constants (P=59, Q=61) ----
static constexpr uint32_t PP  = 59, QQ = 61;
static constexpr uint32_t Nn  = PP * QQ;        // 3599
static constexpr uint32_t P2  = PP * PP;        // 3481
static constexpr uint32_t Q2  = QQ * QQ;        // 3721
static constexpr uint32_t LAM = 1740;           // lcm(58,60)

constexpr uint32_t cinv(uint32_t a, uint32_t m) {   // brute-force modular inverse
    for (uint32_t x = 1; x < m; ++x) if ((uint64_t)a * x % m == 1u) return x;
    return 0u;
}
static constexpr uint32_t MUc = cinv(LAM % Nn, Nn);   // lambda^-1 mod n
static constexpr uint32_t IQP = cinv(P2 % Q2, Q2);    // (p^2)^-1 mod q^2

static constexpr int TPAD = 3484;                // Tp region padded (3481 -> 3484)
static constexpr int TQL  = 3722;                // Tq region padded (3721 -> 3722)
static constexpr int TTOT = TPAD + TQL;          // 7206 u16 = 14412 B of LDS

// ---- full-rate 24-bit multiplies ----
// v_mul_lo_u32/v_mul_hi_u32 are quarter rate on CDNA; u24 forms are full rate.
// All operands below are provably < 2^24.
__device__ __forceinline__ uint32_t mul24lo(uint32_t a, uint32_t b) {
    uint32_t r;
    asm("v_mul_u32_u24 %0, %1, %2" : "=v"(r) : "v"(a), "v"(b));
    return r;
}
__device__ __forceinline__ uint32_t mul24hi(uint32_t a, uint32_t b) {
    uint32_t r;                                   // (u24(a)*u24(b)) >> 32
    asm("v_mul_hi_u32_u24 %0, %1, %2" : "=v"(r) : "v"(a), "v"(b));
    return r;
}

// x < 2^24, D < 4096: x mod D. M = floor(2^35/D) < 2^24; q = (x*M)>>35
// underestimates floor(x/D) by < x/2^35 < 2^-11, so q ∈ {Q-1, Q}; one
// min-correction suffices. Exact for all x < 2^24.
template<uint32_t D>
__device__ __forceinline__ uint32_t mod_small(uint32_t x) {
    constexpr uint32_t M = (uint32_t)((1ull << 35) / D);
    uint32_t q = mul24hi(x, M) >> 3;          // floor(x*M / 2^35)
    uint32_t r = x - mul24lo(q, D);           // ∈ [0, 2D)
    r = min(r, r - D);                        // unsigned wrap trick
    return r;
}

// ---- table entry: i^1740 mod MOD (block prologue; ~11 iters, negligible) ----
template<uint32_t MOD>
__device__ uint32_t powmod1740(uint32_t base) {
    uint32_t b = base, r = 1u, e = LAM;
    while (e) {
        if (e & 1u) r = (r * b) % MOD;        // products < MOD^2 < 2^24; const mod
        b = (b * b) % MOD;
        e >>= 1u;
    }
    return r;
}

// ---- per-element decrypt: exact integer path for ALL c (incl. gcd(c,n)>1) ----
__device__ __forceinline__ float dec1(uint32_t c, const uint16_t* sTp,
                                      const uint16_t* sTq, float scale) {
    uint32_t a = sTp[mod_small<P2>(c)];       // c^1740 mod p^2
    uint32_t b = sTq[mod_small<Q2>(c)];       // c^1740 mod q^2
    // Garner CRT: r = a + p^2 * (((b-a) mod q^2) * IQP mod q^2)
    uint32_t d0 = b + Q2 - a;
    d0 = min(d0, d0 - Q2);                    // (b-a) mod q^2
    uint32_t t = mod_small<Q2>(mul24lo(d0, IQP));   // d0*IQP < 3721*1876 < 2^23
    uint32_t r = a + mul24lo(t, P2);          // c^1740 mod n^2 ∈ [0, n^2)
    // L = (r-1)//n with Python floor semantics: r==0 -> -1 -> m = 2480.
    // Map r==0 to rm1 = 3598*3599 so the same exact division yields L≡3598.
    uint32_t rm1 = (r == 0u) ? (3598u * Nn) : (r - 1u);
    constexpr uint32_t MN = (uint32_t)((1ull << 35) / Nn);
    uint32_t q   = mul24hi(rm1, MN) >> 3;
    uint32_t rem = rm1 - mul24lo(q, Nn);      // ∈ [0, 2n)
    q += (rem >= Nn) ? 1u : 0u;               // exact floor((r-1)/n)
    uint32_t m = mod_small<Nn>(mul24lo(q, MUc));    // q*MU < 3598*1119 < 2^22
    return fmaxf((float)m * scale, 0.0f);     // relu(m * (inv_scale/1000))
}

#define BLK 256

__global__ __launch_bounds__(BLK) void paillier_main(
        const uint4* __restrict__ in4, float4* __restrict__ out,
        const float* __restrict__ inv_scale, int n4) {
    __shared__ uint32_t sT32[TTOT / 2];       // u32-declared => 4B aligned
    uint16_t* sTp = (uint16_t*)sT32;
    uint16_t* sTq = sTp + TPAD;

    // Build both tables in-block (no global scratch). Pad slots never read.
    for (int i = threadIdx.x; i < (int)P2; i += BLK)
        sTp[i] = (uint16_t)powmod1740<P2>((uint32_t)i);
    for (int i = threadIdx.x; i < (int)Q2; i += BLK)
        sTq[i] = (uint16_t)powmod1740<Q2>((uint32_t)i);
    __syncthreads();

    float scale = inv_scale[0] / 1000.0f;     // matches reference fp32 op order

    int stride = gridDim.x * BLK;
    for (int i = blockIdx.x * BLK + threadIdx.x; i < n4; i += stride) {
        // Input is int32 (harness converts integer inputs to int); one uint4
        // load = 4 ciphertexts, each < n^2 < 2^24.
        uint4 a = in4[i];
        float4 o;
        o.x = dec1(a.x, sTp, sTq, scale);
        o.y = dec1(a.y, sTp, sTq, scale);
        o.z = dec1(a.z, sTp, sTq, scale);
        o.w = dec1(a.w, sTp, sTq, scale);
        out[i] = o;
    }
}

extern "C" void kernel_launch(void* const* d_in, const int* in_sizes, int n_in,
                              void* d_out, int out_size, void* d_ws, size_t ws_size,
                              hipStream_t stream) {
    const uint4* c        = (const uint4*)d_in[0];     // int32 data, read as uint4
    const float* invscale = (const float*)d_in[1];
    float4* out           = (float4*)d_out;

    int n  = in_sizes[0];                              // 33,554,432 (divisible by 4)
    int n4 = n / 4;                                    // uint4 groups

    int nblk = 2048;                                   // grid-stride, 8 blocks/CU
    int need = (n4 + BLK - 1) / BLK;
    if (nblk > need) nblk = need;
    paillier_main<<<nblk, BLK, 0, stream>>>(c, out, invscale, n4);
}

// Round 4
// 236.438 us; speedup vs baseline: 1.0355x; 1.0355x over previous
//
#include <hip/hip_runtime.h>
#include <stdint.h>

// ---- Paillier constants (P=59, Q=61) ----
static constexpr uint32_t PP  = 59, QQ = 61;
static constexpr uint32_t Nn  = PP * QQ;        // 3599
static constexpr uint32_t P2  = PP * PP;        // 3481
static constexpr uint32_t Q2  = QQ * QQ;        // 3721
static constexpr uint32_t LAM = 1740;           // lcm(58,60)

constexpr uint32_t cinv(uint32_t a, uint32_t m) {   // brute-force modular inverse
    for (uint32_t x = 1; x < m; ++x) if ((uint64_t)a * x % m == 1u) return x;
    return 0u;
}
static constexpr uint32_t MUc = cinv(LAM % Nn, Nn);   // lambda^-1 mod n
static constexpr uint32_t IQP = cinv(P2 % Q2, Q2);    // (p^2)^-1 mod q^2

static constexpr int TPAD = 3484;                // Tp region padded (3481 -> 3484)
static constexpr int TQL  = 3722;                // Tq region padded (3721 -> 3722)
static constexpr int TTOT = TPAD + TQL;          // 7206 u16 = 14412 B
static constexpr size_t WS_NEED = (size_t)TTOT * 2;

// ---- full-rate 24-bit multiplies ----
// v_mul_lo_u32/v_mul_hi_u32 are quarter rate on CDNA; u24 forms are full rate.
// All operands below are provably < 2^24.
__device__ __forceinline__ uint32_t mul24lo(uint32_t a, uint32_t b) {
    uint32_t r;
    asm("v_mul_u32_u24 %0, %1, %2" : "=v"(r) : "v"(a), "v"(b));
    return r;
}
__device__ __forceinline__ uint32_t mul24hi(uint32_t a, uint32_t b) {
    uint32_t r;                                   // (u24(a)*u24(b)) >> 32
    asm("v_mul_hi_u32_u24 %0, %1, %2" : "=v"(r) : "v"(a), "v"(b));
    return r;
}

// x < 2^24, D < 4096: x mod D. M = floor(2^35/D) < 2^24; q = (x*M)>>35
// underestimates floor(x/D) by < x/2^35 < 2^-11, so one min-correction
// suffices. Exact for all x < 2^24.
template<uint32_t D>
__device__ __forceinline__ uint32_t mod_small(uint32_t x) {
    constexpr uint32_t M = (uint32_t)((1ull << 35) / D);
    uint32_t q = mul24hi(x, M) >> 3;          // floor(x*M / 2^35)
    uint32_t r = x - mul24lo(q, D);           // ∈ [0, 2D)
    r = min(r, r - D);                        // unsigned wrap trick
    return r;
}

// ---- table entry: i^1740 mod MOD ----
template<uint32_t MOD>
__device__ uint32_t powmod1740(uint32_t base) {
    uint32_t b = base, r = 1u, e = LAM;
    while (e) {
        if (e & 1u) r = (r * b) % MOD;        // products < MOD^2 < 2^24; const mod
        b = (b * b) % MOD;
        e >>= 1u;
    }
    return r;
}

// One-time table build into d_ws: 3721 threads, ~11 iters each. Cost < 5 us.
__global__ void build_tables(uint16_t* __restrict__ T) {
    int i = blockIdx.x * blockDim.x + threadIdx.x;
    if (i < (int)P2) T[i]        = (uint16_t)powmod1740<P2>((uint32_t)i);
    if (i < (int)Q2) T[TPAD + i] = (uint16_t)powmod1740<Q2>((uint32_t)i);
}

// ---- per-element decrypt: exact integer path for ALL c (incl. gcd(c,n)>1) ----
__device__ __forceinline__ float dec1(uint32_t c, const uint16_t* sTp,
                                      const uint16_t* sTq, float scale) {
    uint32_t a = sTp[mod_small<P2>(c)];       // c^1740 mod p^2
    uint32_t b = sTq[mod_small<Q2>(c)];       // c^1740 mod q^2
    // Garner CRT: r = a + p^2 * (((b-a) mod q^2) * IQP mod q^2)
    uint32_t d0 = b + Q2 - a;
    d0 = min(d0, d0 - Q2);                    // (b-a) mod q^2
    uint32_t t = mod_small<Q2>(mul24lo(d0, IQP));   // d0*IQP < 3721*1876 < 2^23
    uint32_t r = a + mul24lo(t, P2);          // c^1740 mod n^2 ∈ [0, n^2)
    // L = (r-1)//n with Python floor semantics: r==0 -> -1 -> m = 2480.
    // Map r==0 to rm1 = 3598*3599 so the same exact division yields L≡3598.
    uint32_t rm1 = (r == 0u) ? (3598u * Nn) : (r - 1u);
    constexpr uint32_t MN = (uint32_t)((1ull << 35) / Nn);
    uint32_t q   = mul24hi(rm1, MN) >> 3;
    uint32_t rem = rm1 - mul24lo(q, Nn);      // ∈ [0, 2n)
    q += (rem >= Nn) ? 1u : 0u;               // exact floor((r-1)/n)
    uint32_t m = mod_small<Nn>(mul24lo(q, MUc));    // q*MU < 3598*1119 < 2^22
    return fmaxf((float)m * scale, 0.0f);     // relu(m * (inv_scale/1000))
}

#define BLK 256

// Main kernel: stages tables from global (built once by build_tables).
__global__ __launch_bounds__(BLK) void paillier_main(
        const uint4* __restrict__ in4, float4* __restrict__ out,
        const uint16_t* __restrict__ T, const float* __restrict__ inv_scale,
        int n4) {
    __shared__ uint32_t sT32[TTOT / 2];       // u32-declared => 4B aligned
    {   // ~15 coalesced u32 loads per thread (L2/L3-hit after first blocks)
        const uint32_t* Ts = (const uint32_t*)T;
        for (int k = threadIdx.x; k < TTOT / 2; k += BLK) sT32[k] = Ts[k];
    }
    __syncthreads();
    const uint16_t* sTp = (const uint16_t*)sT32;
    const uint16_t* sTq = sTp + TPAD;

    float scale = inv_scale[0] / 1000.0f;     // matches reference fp32 op order

    int stride = gridDim.x * BLK;
    for (int i = blockIdx.x * BLK + threadIdx.x; i < n4; i += stride) {
        uint4 a = in4[i];                     // 4 int32 ciphertexts, each < 2^24
        float4 o;
        o.x = dec1(a.x, sTp, sTq, scale);
        o.y = dec1(a.y, sTp, sTq, scale);
        o.z = dec1(a.z, sTp, sTq, scale);
        o.w = dec1(a.w, sTp, sTq, scale);
        out[i] = o;
    }
}

// Fallback (ws too small): build tables in-block — the verified R3 kernel.
__global__ __launch_bounds__(BLK) void paillier_main_fb(
        const uint4* __restrict__ in4, float4* __restrict__ out,
        const float* __restrict__ inv_scale, int n4) {
    __shared__ uint32_t sT32[TTOT / 2];
    uint16_t* sTp = (uint16_t*)sT32;
    uint16_t* sTq = sTp + TPAD;
    for (int i = threadIdx.x; i < (int)P2; i += BLK)
        sTp[i] = (uint16_t)powmod1740<P2>((uint32_t)i);
    for (int i = threadIdx.x; i < (int)Q2; i += BLK)
        sTq[i] = (uint16_t)powmod1740<Q2>((uint32_t)i);
    __syncthreads();
    float scale = inv_scale[0] / 1000.0f;
    int stride = gridDim.x * BLK;
    for (int i = blockIdx.x * BLK + threadIdx.x; i < n4; i += stride) {
        uint4 a = in4[i];
        float4 o;
        o.x = dec1(a.x, sTp, sTq, scale);
        o.y = dec1(a.y, sTp, sTq, scale);
        o.z = dec1(a.z, sTp, sTq, scale);
        o.w = dec1(a.w, sTp, sTq, scale);
        out[i] = o;
    }
}

extern "C" void kernel_launch(void* const* d_in, const int* in_sizes, int n_in,
                              void* d_out, int out_size, void* d_ws, size_t ws_size,
                              hipStream_t stream) {
    const uint4* c        = (const uint4*)d_in[0];     // int32 data, read as uint4
    const float* invscale = (const float*)d_in[1];
    float4* out           = (float4*)d_out;

    int n  = in_sizes[0];                              // 33,554,432 (divisible by 4)
    int n4 = n / 4;

    int nblk = 2048;                                   // grid-stride, 8 blocks/CU
    int need = (n4 + BLK - 1) / BLK;
    if (nblk > need) nblk = need;

    if (ws_size >= WS_NEED && d_ws != nullptr) {
        uint16_t* T = (uint16_t*)d_ws;
        build_tables<<<(Q2 + 255) / 256, 256, 0, stream>>>(T);
        paillier_main<<<nblk, BLK, 0, stream>>>(c, out, T, invscale, n4);
    } else {
        paillier_main_fb<<<nblk, BLK, 0, stream>>>(c, out, invscale, n4);
    }
}

// Round 5
// 235.423 us; speedup vs baseline: 1.0399x; 1.0043x over previous
//
#include <hip/hip_runtime.h>
#include <stdint.h>

// ---- Paillier constants (P=59, Q=61) ----
static constexpr uint32_t PP  = 59, QQ = 61;
static constexpr uint32_t Nn  = PP * QQ;        // 3599
static constexpr uint32_t P2  = PP * PP;        // 3481
static constexpr uint32_t Q2  = QQ * QQ;        // 3721
static constexpr uint32_t LAM = 1740;           // lcm(58,60)

constexpr uint32_t cinv(uint32_t a, uint32_t m) {   // brute-force modular inverse
    for (uint32_t x = 1; x < m; ++x) if ((uint64_t)a * x % m == 1u) return x;
    return 0u;
}
static constexpr uint32_t MU  = cinv(LAM % Nn, Nn);   // 1119 = lambda^-1 mod n
static constexpr uint32_t IQP = cinv(P2 % Q2, Q2);    // (p^2)^-1 mod q^2
static constexpr uint32_t GAM = cinv(PP % QQ, QQ);    // p^-1 mod q = 30
static constexpr uint32_t CPP = (cinv(QQ % PP, PP) * (MU % PP)) % PP;  // q^-1*mu mod p
static constexpr uint32_t CQQ = (cinv(PP % QQ, QQ) * (MU % QQ)) % QQ;  // p^-1*mu mod q

static constexpr int TPN = 3484;                // Tp u32 count (3481 padded to /4)
static constexpr int TQN = 3724;                // Tq u32 count (3721 padded to /4)
static constexpr int TT  = TPN + TQN;           // 7208 u32 = 28832 B
static constexpr size_t WS_NEED = (size_t)TT * 4;

// ---- full-rate 24-bit multiplies (operands provably < 2^24) ----
__device__ __forceinline__ uint32_t mul24lo(uint32_t a, uint32_t b) {
    uint32_t r;
    asm("v_mul_u32_u24 %0, %1, %2" : "=v"(r) : "v"(a), "v"(b));
    return r;
}
__device__ __forceinline__ uint32_t mul24hi(uint32_t a, uint32_t b) {
    uint32_t r;                                   // (u24(a)*u24(b)) >> 32
    asm("v_mul_hi_u32_u24 %0, %1, %2" : "=v"(r) : "v"(a), "v"(b));
    return r;
}
__device__ __forceinline__ uint32_t mad24_59(uint32_t a, uint32_t c) {
    uint32_t r;                                   // a*59 + c, all < 2^24
    asm("v_mad_u32_u24 %0, %1, 59, %2" : "=v"(r) : "v"(a), "v"(c));
    return r;
}

// x < 2^24, D ~ 3500: x mod D via 2^32 magic (no shift needed).
// M = floor(2^32/D) < 2^24; q = (x*M)>>32 underestimates floor(x/D) by
// < x/2^32 < 2^-8, so q ∈ {Q-1, Q}; one min-correction suffices. Exact.
template<uint32_t D>
__device__ __forceinline__ uint32_t mod24(uint32_t x) {
    constexpr uint32_t M = (uint32_t)((1ull << 32) / D);
    uint32_t q = mul24hi(x, M);
    uint32_t r = x - mul24lo(q, D);           // ∈ [0, 2D)
    return min(r, r - D);                     // unsigned wrap trick
}

// ---- table construction (exact; runs once over 3724 threads) ----
template<uint32_t MOD>
__device__ uint32_t pow1740(uint32_t base) {
    uint32_t b = base % MOD, r = 1u, e = LAM;
    while (e) {                               // products < MOD^2 < 2^24
        if (e & 1u) r = (r * b) % MOD;
        b = (b * b) % MOD;
        e >>= 1u;
    }
    return r;
}
// m = ((r-1)//n * mu) mod n with Python floor semantics; r = c^lam mod n^2.
__device__ uint32_t m_from_r(uint32_t r) {
    if (r == 0u) return Nn - MU;              // x = -1 -> (-mu) mod n = 2480
    uint32_t x = (r - 1u) / Nn;               // exact floor, x < n
    return (x * MU) % Nn;                     // < 3599*1119 < 2^22
}
// Tp[ip]: bits0-5 g_p, bits8-13 m_p, bits16-27 dq_val (m when q|c), bit31 p|ip
__device__ uint32_t tp_entry(uint32_t i) {
    uint32_t a = pow1740<P2>(i);              // c^lam mod p^2 (0 iff p|i)
    uint32_t flag = (i % PP == 0u) ? 0x80000000u : 0u;
    uint32_t gp = 0u, mp = 0u;
    if (!flag) {                              // a ≡ 1 mod p; s = (a-1)/p
        uint32_t s = (a - 1u) / PP;
        mp = (s * CPP) % PP;                  // m mod p
        gp = (mp * GAM) % QQ;
    }
    // dq_val: m given q|c (b=0): r ≡ a (p^2), ≡ 0 (q^2), Garner with b=0
    uint32_t t = (uint32_t)(((uint64_t)((Q2 - a % Q2) % Q2) * IQP) % Q2);
    uint32_t r = a + P2 * t;                  // < n^2, exact
    uint32_t dq = m_from_r(r);                // flag case: a=0 -> r=0 -> 2480
    return gp | (mp << 8) | (dq << 16) | flag;
}
// Tq[iq]: bits0-5 g_q, bits16-27 dp_val (m when p|c), bit31 q|iq
__device__ uint32_t tq_entry(uint32_t i) {
    uint32_t b = pow1740<Q2>(i);              // c^lam mod q^2 (0 iff q|i)
    uint32_t flag = (i % QQ == 0u) ? 0x80000000u : 0u;
    uint32_t gq = 0u;
    if (!flag) {
        uint32_t s = (b - 1u) / QQ;
        uint32_t mq = (s * CQQ) % QQ;         // m mod q
        gq = (mq * GAM) % QQ;
    }
    // dp_val: m given p|c (a=0): r ≡ 0 (p^2), ≡ b (q^2)
    uint32_t t = (uint32_t)(((uint64_t)b * IQP) % Q2);
    uint32_t r = P2 * t;                      // < n^2, exact
    uint32_t dp = m_from_r(r);                // flag case: b=0 -> r=0 -> 2480
    return gq | (dp << 16) | flag;
}

__global__ void build_tables(uint32_t* __restrict__ T) {
    int i = blockIdx.x * blockDim.x + threadIdx.x;
    if (i < TPN) T[i]       = (i < (int)P2) ? tp_entry((uint32_t)i) : 0u;
    if (i < TQN) T[TPN + i] = (i < (int)Q2) ? tq_entry((uint32_t)i) : 0u;
}

// ---- per-element decrypt: ~27 VALU ops + 2 LDS gathers, exact for ALL c ----
__device__ __forceinline__ float dec1(uint32_t c, const uint32_t* sTp,
                                      const uint32_t* sTq, float scale) {
    uint32_t up = sTp[mod24<P2>(c)];
    uint32_t uq = sTq[mod24<Q2>(c)];
    uint32_t gp  = up & 63u;
    uint32_t mp  = (up >> 8) & 63u;
    uint32_t dqv = (up >> 16) & 0xFFFu;
    uint32_t gq  = uq & 63u;
    uint32_t dpv = (uq >> 16) & 0xFFFu;
    uint32_t d = gq + QQ - gp;                // (m_q - m_p)*p^-1 mod q, premult
    d = min(d, d - QQ);
    uint32_t m = mad24_59(d, mp);             // CRT: m_p + 59*d ∈ [0, 3599)
    m = ((int32_t)uq < 0) ? dqv : m;          // q|c: table value from ip
    m = ((int32_t)up < 0) ? dpv : m;          // p|c: table value from iq (2480 if both)
    return fmaxf((float)m * scale, 0.0f);     // relu(m * (inv_scale/1000))
}

#define BLK 512

// 1024 blocks x 512 thr: 4 blocks/CU co-resident (28.8KB LDS, 32 waves/CU),
// 16 exact iterations/thread, no tail.
__global__ __launch_bounds__(BLK, 8) void paillier_main(
        const uint4* __restrict__ in4, float4* __restrict__ out,
        const uint32_t* __restrict__ T, const float* __restrict__ inv_scale,
        int n4) {
    __shared__ uint32_t sT[TT];
    for (int k = threadIdx.x; k < TT / 4; k += BLK)
        ((uint4*)sT)[k] = ((const uint4*)T)[k];
    __syncthreads();
    const uint32_t* sTp = sT;
    const uint32_t* sTq = sT + TPN;

    float scale = inv_scale[0] / 1000.0f;     // matches reference fp32 op order

    int stride = gridDim.x * BLK;
    for (int i = blockIdx.x * BLK + threadIdx.x; i < n4; i += stride) {
        uint4 a = in4[i];                     // 4 int32 ciphertexts, each < 2^24
        float4 o;
        o.x = dec1(a.x, sTp, sTq, scale);
        o.y = dec1(a.y, sTp, sTq, scale);
        o.z = dec1(a.z, sTp, sTq, scale);
        o.w = dec1(a.w, sTp, sTq, scale);
        out[i] = o;
    }
}

// Fallback (ws too small): build packed tables in-block, same dec path.
__global__ __launch_bounds__(BLK) void paillier_main_fb(
        const uint4* __restrict__ in4, float4* __restrict__ out,
        const float* __restrict__ inv_scale, int n4) {
    __shared__ uint32_t sT[TT];
    for (int i = threadIdx.x; i < (int)P2; i += BLK) sT[i]       = tp_entry((uint32_t)i);
    for (int i = threadIdx.x; i < (int)Q2; i += BLK) sT[TPN + i] = tq_entry((uint32_t)i);
    __syncthreads();
    const uint32_t* sTp = sT;
    const uint32_t* sTq = sT + TPN;
    float scale = inv_scale[0] / 1000.0f;
    int stride = gridDim.x * BLK;
    for (int i = blockIdx.x * BLK + threadIdx.x; i < n4; i += stride) {
        uint4 a = in4[i];
        float4 o;
        o.x = dec1(a.x, sTp, sTq, scale);
        o.y = dec1(a.y, sTp, sTq, scale);
        o.z = dec1(a.z, sTp, sTq, scale);
        o.w = dec1(a.w, sTp, sTq, scale);
        out[i] = o;
    }
}

extern "C" void kernel_launch(void* const* d_in, const int* in_sizes, int n_in,
                              void* d_out, int out_size, void* d_ws, size_t ws_size,
                              hipStream_t stream) {
    const uint4* c        = (const uint4*)d_in[0];     // int32 data, read as uint4
    const float* invscale = (const float*)d_in[1];
    float4* out           = (float4*)d_out;

    int n  = in_sizes[0];                              // 33,554,432
    int n4 = n / 4;

    int nblk = 1024;                                   // 4 blocks/CU, all resident
    int need = (n4 + BLK - 1) / BLK;
    if (nblk > need) nblk = need;

    if (ws_size >= WS_NEED && d_ws != nullptr) {
        uint32_t* T = (uint32_t*)d_ws;
        build_tables<<<(TQN + 255) / 256, 256, 0, stream>>>(T);
        paillier_main<<<nblk, BLK, 0, stream>>>(c, out, T, invscale, n4);
    } else {
        paillier_main_fb<<<nblk, BLK, 0, stream>>>(c, out, invscale, n4);
    }
}